// Round 4
// baseline (62.726 us; speedup 1.0000x reference)
//
#include <hip/hip_runtime.h>

// ACT-R activation recurrence, in-register triangle.
// s_i = sum_{j<i} ((t_i-t_j)*H)^(-decay_j),  decay_j = w0 + w1*s_j  (s_0=0)
// (the reference's max(diff*H,1) never binds: min gap 0.05 days * 2160 = 108)
// out[i-1,b] = sigmoid((ln(s_i)-TAU)/S), i=1..L-1.
//
// Key identity: diff^(-decay_j) = exp2(q_ij*(s_j + w0/w1)), q_ij = -w1*log2(diff_ij).
// With shifted accumulator alpha = s + w0/w1, the triangle needs ONE float per
// pair, masked entries use q=-1e30 (term -> 0), and -decay_j = -w1*alpha_j.
//
// Per phase k (T=64 rows):
//  wave 0: prefetch 64 q-values (16x ds_read_b128, XOR-swizzled, conflict-free)
//  all:    STRIP — apply col-block k-1 to block-k rows (16 thr/row, shfl reduce)
//  barrier
//  wave 0: TRIANGLE — pure-register 64-step chain: rdlane -> mul -> exp2 -> add
//  waves 1-15: PANEL (col k-1 -> rows >= I0+T) + build next block's qT
//  barrier

constexpr int   L  = 1024;
constexpr int   B  = 256;
constexpr int   T  = 64;
constexpr int   NT = 1024;   // 16 waves

constexpr float H_CONST = 86400.0f * 0.025f;   // 2160
constexpr float TAU_C   = -0.704205679427144f;
constexpr float S_C     = 0.254893976981164f;
constexpr float LN2     = 0.69314718055994530942f;
constexpr float LOG2E   = 1.4426950408889634074f;
constexpr float BIGNEG  = -1e30f;

__device__ __forceinline__ float flog2(float x) { return __builtin_amdgcn_logf(x); }
__device__ __forceinline__ float fexp2(float x) { return __builtin_amdgcn_exp2f(x); }
__device__ __forceinline__ float rdlane(float v, int l) {
    return __uint_as_float(__builtin_amdgcn_readlane(__float_as_uint(v), l));
}

__global__ __launch_bounds__(NT)
void actr_kernel(const float* __restrict__ sp, const float* __restrict__ w,
                 float* __restrict__ out)
{
    __shared__ float  tH[L];        // t_i * H
    __shared__ float  acc[L];       // partial sums (col-blocks < k-1)
    __shared__ float2 col[L];       // finalized columns {t_j, -decay_j}
    __shared__ float  qT[2][T * T]; // swizzled: P(l,j) = l*64 + (j ^ (4*(l&15)))
    __shared__ float  stripsum[T];  // col-block k-1 applied to block-k rows

    const int b   = blockIdx.x;
    const int tid = threadIdx.x;
    const float w0  = w[0];
    const float w1  = w[1];
    const float CSH = w0 / w1;      // accumulator shift

    for (int i = tid; i < L; i += NT) {
        tH[i]  = sp[i * B + b] * H_CONST;
        acc[i] = 0.0f;
    }
    if (tid < T) stripsum[tid] = 0.0f;
    __syncthreads();

    // prologue: qT[0] for block 0 (each wave: l2 fixed, j = lane -> 2-way-max writes)
    for (int f = tid; f < T * T; f += NT) {
        const int j = f & 63, l2 = f >> 6;
        const float q = (j < l2) ? (-w1 * flog2(tH[l2] - tH[j])) : BIGNEG;
        qT[0][l2 * 64 + (j ^ (4 * (l2 & 15)))] = q;
    }
    __syncthreads();

    for (int k = 0; k < L / T; ++k) {
        const int I0 = k * T;

        // ---- wave 0: prefetch this block's q into registers (hidden under strip)
        float4 qreg[16];
        float  acc_r = 0.0f;
        if (tid < 64) {
            const float* qb = &qT[k & 1][0] + tid * 64;
            #pragma unroll
            for (int g = 0; g < 16; ++g)
                qreg[g] = *reinterpret_cast<const float4*>(qb + 4 * (g ^ (tid & 15)));
            acc_r = acc[I0 + tid];   // final since end of phase k-1
        }

        // ---- strip: all 1024 threads, 16 per block-k row ----
        if (k > 0) {
            const int rl = tid >> 4, c = tid & 15, base = I0 - T;
            const float my_t = tH[I0 + rl];
            float p = 0.0f;
            #pragma unroll
            for (int u = 0; u < 4; ++u) {
                const float2 cj = col[base + c + 16 * u];
                p += fexp2(cj.y * flog2(my_t - cj.x));
            }
            p += __shfl_xor(p, 1);
            p += __shfl_xor(p, 2);
            p += __shfl_xor(p, 4);
            p += __shfl_xor(p, 8);
            if (c == 0) stripsum[rl] = p;
        }
        __syncthreads();

        if (tid < 64) {
            // ---- pure-register serial triangle ----
            const int l = tid;
            const int r = I0 + l;
            float alpha = acc_r + stripsum[l] + CSH;
            __builtin_amdgcn_s_setprio(1);
            #pragma unroll
            for (int g = 0; g < 16; ++g) {
                #pragma unroll
                for (int u = 0; u < 4; ++u) {
                    const float sig = rdlane(alpha, 4 * g + u); // sigma_j (const lane)
                    alpha += fexp2(qreg[g][u] * sig);
                }
            }
            __builtin_amdgcn_s_setprio(0);
            col[r] = make_float2(tH[r], -w1 * alpha);   // -decay_r = -w1*alpha_r
            if (r > 0) {
                const float act = flog2(alpha - CSH) * LN2;     // ln(s_r)
                const float e   = fexp2((TAU_C - act) * (LOG2E / S_C));
                out[(r - 1) * B + b] = 1.0f / (1.0f + e);
            }
        } else {
            // ---- panel: col-block k-1 -> rows >= I0+T ----
            if (k > 0) {
                const int r = I0 + T + (tid - 64);
                if (r < L) {
                    const int base = I0 - T;
                    float a = acc[r];
                    const float my_t = tH[r];
                    #pragma unroll 16
                    for (int j = 0; j < T; ++j) {
                        const float2 cj = col[base + j];    // broadcast read
                        a += fexp2(cj.y * flog2(my_t - cj.x));
                    }
                    acc[r] = a;
                }
            }
            // ---- build next block's qT (timestamps only) ----
            if (k < L / T - 1) {
                const int I1 = I0 + T;
                float* qn = &qT[(k + 1) & 1][0];
                for (int f = tid - 64; f < T * T; f += NT - 64) {
                    const int j = f & 63, l2 = f >> 6;
                    const float q = (j < l2) ? (-w1 * flog2(tH[I1 + l2] - tH[I1 + j]))
                                             : BIGNEG;
                    qn[l2 * 64 + (j ^ (4 * (l2 & 15)))] = q;
                }
            }
        }
        __syncthreads();
    }
}

extern "C" void kernel_launch(void* const* d_in, const int* in_sizes, int n_in,
                              void* d_out, int out_size, void* d_ws, size_t ws_size,
                              hipStream_t stream) {
    const float* sp = (const float*)d_in[0];
    const float* w  = (const float*)d_in[1];
    float* out      = (float*)d_out;
    actr_kernel<<<dim3(B), dim3(NT), 0, stream>>>(sp, w, out);
}

// Round 5
// 60.768 us; speedup vs baseline: 1.0322x; 1.0322x over previous
//
#include <hip/hip_runtime.h>

// ACT-R activation recurrence — DS-pipe-decongested version.
// s_i = sum_{j<i} ((t_i-t_j)*H)^(-decay_j),  decay_j = w0 + w1*s_j  (s_0=0)
// (reference's max(diff*H,1) never binds: min gap 0.05 days * 2160 = 108)
// out[i-1,b] = sigmoid((ln(s_i)-TAU)/S), i=1..L-1.
//
// Identity: diff^(-decay_j) = exp2(q_ij * alpha_j), q_ij = -w1*log2(diff_ij),
// alpha = s + w0/w1 (shifted accumulator); masked entries q = -1e30 -> term 0.
//
// Key change vs R4: the LDS DS pipe is per-CU and was saturated by per-pair
// broadcast col[] reads (960 wave-reads/phase). Panels now load the col block
// ONCE per wave into per-lane registers and broadcast via v_readlane (VALU,
// 4 SIMDs wide). Triangle prefetch is chunked (2x 4xfloat4 named buffers) so
// it can't spill and LDS latency hides under the previous chunk's chain.

constexpr int   L  = 1024;
constexpr int   B  = 256;
constexpr int   T  = 64;
constexpr int   NT = 1024;   // 16 waves

constexpr float H_CONST = 86400.0f * 0.025f;   // 2160
constexpr float TAU_C   = -0.704205679427144f;
constexpr float S_C     = 0.254893976981164f;
constexpr float LN2     = 0.69314718055994530942f;
constexpr float LOG2E   = 1.4426950408889634074f;
constexpr float BIGNEG  = -1e30f;

__device__ __forceinline__ float flog2(float x) { return __builtin_amdgcn_logf(x); }
__device__ __forceinline__ float fexp2(float x) { return __builtin_amdgcn_exp2f(x); }
__device__ __forceinline__ float rdlane(float v, int l) {
    return __uint_as_float(__builtin_amdgcn_readlane(__float_as_uint(v), l));
}

// load one 16-step chunk (groups 4c..4c+3) of this lane's swizzled q row
#define LOADCH(p0, p1, p2, p3, c)                                   \
    p0 = *(const float4*)(qb + 4 * ((4 * (c) + 0) ^ xk));           \
    p1 = *(const float4*)(qb + 4 * ((4 * (c) + 1) ^ xk));           \
    p2 = *(const float4*)(qb + 4 * ((4 * (c) + 2) ^ xk));           \
    p3 = *(const float4*)(qb + 4 * ((4 * (c) + 3) ^ xk));

#define RUN4(qv, J)                                                  \
    { float sg;                                                      \
      sg = rdlane(alpha, (J) + 0); alpha += fexp2(qv.x * sg);        \
      sg = rdlane(alpha, (J) + 1); alpha += fexp2(qv.y * sg);        \
      sg = rdlane(alpha, (J) + 2); alpha += fexp2(qv.z * sg);        \
      sg = rdlane(alpha, (J) + 3); alpha += fexp2(qv.w * sg); }

#define RUN16(q0, q1, q2, q3, J) \
    RUN4(q0, J) RUN4(q1, (J) + 4) RUN4(q2, (J) + 8) RUN4(q3, (J) + 12)

__global__ __launch_bounds__(NT)
void actr_kernel(const float* __restrict__ sp, const float* __restrict__ w,
                 float* __restrict__ out)
{
    __shared__ float  tH[L];        // t_i * H
    __shared__ float  acc[L];       // partial sums (col-blocks <= k-2)
    __shared__ float2 col[L];       // finalized columns {t_j, -decay_j}
    __shared__ float  qT[2][T * T]; // swizzled: row l, elem (j ^ 4*(l&15))
    __shared__ float  stripsum[T];

    const int b    = blockIdx.x;
    const int tid  = threadIdx.x;
    const int lane = tid & 63;
    const int wv   = tid >> 6;
    const float w0  = w[0];
    const float w1  = w[1];
    const float CSH = w0 / w1;

    for (int i = tid; i < L; i += NT) {
        tH[i]  = sp[i * B + b] * H_CONST;
        acc[i] = 0.0f;
    }
    if (tid < T) stripsum[tid] = 0.0f;
    __syncthreads();

    // prologue: build qT[0] for block 0
    for (int f = tid; f < T * T; f += NT) {
        const int j = f & 63, l2 = f >> 6;
        const float q = (j < l2) ? (-w1 * flog2(tH[l2] - tH[j])) : BIGNEG;
        qT[0][l2 * 64 + (j ^ (4 * (l2 & 15)))] = q;
    }
    __syncthreads();

    for (int k = 0; k < L / T; ++k) {
        const int I0 = k * T;
        const int xk = lane & 15;
        const float* qb = &qT[k & 1][lane * 64];

        float4 qA0, qA1, qA2, qA3, qB0, qB1, qB2, qB3;
        float  acc_r = 0.0f;
        if (wv == 0) {
            LOADCH(qA0, qA1, qA2, qA3, 0)     // chunk 0, hidden under strip
            acc_r = acc[I0 + lane];
        }

        // strip: all 1024 threads, 16 per block-k row (cols k-1 -> block k)
        if (k > 0) {
            const int rl = tid >> 4, c = tid & 15;
            const float my_t = tH[I0 + rl];
            const float2* cb = &col[I0 - T];
            float p = 0.0f;
            #pragma unroll
            for (int uu = 0; uu < 4; ++uu) {
                const float2 cj = cb[c + 16 * uu];
                p += fexp2(cj.y * flog2(my_t - cj.x));
            }
            p += __shfl_xor(p, 1);
            p += __shfl_xor(p, 2);
            p += __shfl_xor(p, 4);
            p += __shfl_xor(p, 8);
            if (c == 0) stripsum[rl] = p;
        }
        __syncthreads();

        if (wv == 0) {
            // serial triangle: pure-register chain, chunked LDS prefetch
            float alpha = acc_r + stripsum[lane] + CSH;
            __builtin_amdgcn_s_setprio(1);
            LOADCH(qB0, qB1, qB2, qB3, 1)
            RUN16(qA0, qA1, qA2, qA3, 0)
            LOADCH(qA0, qA1, qA2, qA3, 2)
            RUN16(qB0, qB1, qB2, qB3, 16)
            LOADCH(qB0, qB1, qB2, qB3, 3)
            RUN16(qA0, qA1, qA2, qA3, 32)
            RUN16(qB0, qB1, qB2, qB3, 48)
            __builtin_amdgcn_s_setprio(0);
            const int r = I0 + lane;
            col[r] = make_float2(tH[r], -w1 * alpha);
            if (r > 0) {
                const float act = flog2(alpha - CSH) * LN2;   // ln(s_r)
                const float e   = fexp2((TAU_C - act) * (LOG2E / S_C));
                out[(r - 1) * B + b] = 1.0f / (1.0f + e);
            }
        } else {
            // panel: cols k-1 -> rows >= I0+T, 2 adjacent rows per thread,
            // col block broadcast via readlane (no per-pair DS traffic)
            const int u    = tid - 64;          // 0..959
            const int rows = L - I0 - T;
            if (k > 0 && 2 * u + 1 < rows) {
                const int r0 = I0 + T + 2 * u;
                float2 av = *(float2*)&acc[r0];
                const float2 tv = *(const float2*)&tH[r0];
                const float2 cv = col[I0 - T + lane];   // 1 DS read per wave
                #pragma unroll
                for (int j = 0; j < 64; ++j) {
                    const float st = rdlane(cv.x, j);
                    const float sd = rdlane(cv.y, j);
                    av.x += fexp2(sd * flog2(tv.x - st));
                    av.y += fexp2(sd * flog2(tv.y - st));
                }
                *(float2*)&acc[r0] = av;
            }
            // build next block's qT (timestamps only), readlane broadcast
            if (k < L / T - 1) {
                const int I1 = I0 + T;
                float* qn = &qT[(k + 1) & 1][0];
                const float vt = tH[I1 + lane];     // 1 DS read per wave
                #pragma unroll
                for (int m = 0; m < 5; ++m) {
                    const int l2 = (wv - 1) + 15 * m;
                    if (l2 < 64) {
                        const float tl2 = rdlane(vt, l2);
                        const float q = (lane < l2) ? (-w1 * flog2(tl2 - vt))
                                                    : BIGNEG;
                        qn[l2 * 64 + (lane ^ (4 * (l2 & 15)))] = q;
                    }
                }
            }
        }
        __syncthreads();
    }
}

extern "C" void kernel_launch(void* const* d_in, const int* in_sizes, int n_in,
                              void* d_out, int out_size, void* d_ws, size_t ws_size,
                              hipStream_t stream) {
    const float* sp = (const float*)d_in[0];
    const float* w  = (const float*)d_in[1];
    float* out      = (float*)d_out;
    actr_kernel<<<dim3(B), dim3(NT), 0, stream>>>(sp, w, out);
}